// Round 8
// baseline (411.131 us; speedup 1.0000x reference)
//
#include <hip/hip_runtime.h>

// ContrastiveLoss on MI355X — ROUND 8 = DIAGNOSTIC ROUND.
// Rounds 3-7: five structurally different fused k2 variants all hit 71-72.5us.
// Per-kernel durations are invisible (harness fill kernels ~152-161us occupy
// the whole top-5). This round forces the label scan into the top-5 by
// scanning the 256MB label 4x per kernel (1GB traffic each), as an A/B pair:
//   k_scan<1>: nontemporal u32x4 loads (what every failed variant used)
//   k_scan<0>: plain u32x4 loads (identical code otherwise)
// Reads of their rows: hbm_gbps = attainable scan BW per load type;
// FETCH_SIZE<<1GB on the plain variant = LLC retention (exploitable:
// each timed replay re-reads the same 256MB ~ LLC-sized label).
// k2 is now GEMM+LSE only (no scan). Total dur_us will regress (~400us);
// that is the accepted price of the first direct measurement.

#define NN 8192
#define DD 128

typedef __bf16 bf16x8 __attribute__((ext_vector_type(8)));
typedef float f32x4 __attribute__((ext_vector_type(4)));
typedef unsigned int u32x4 __attribute__((ext_vector_type(4)));

constexpr float kM     = 1.0f / 0.07f;                    // fixed max bound (cos<=1)
constexpr float kScale = 1.4426950408889634f / 0.07f;     // log2(e)/T
constexpr float kLn2   = 0.6931471805599453f;

__device__ inline unsigned short f2bf(float f) {
  unsigned int u = __float_as_uint(f);
  unsigned int r = (u + 0x7FFFu + ((u >> 16) & 1u)) >> 16;  // RNE, no NaN inputs
  return (unsigned short)r;
}

// ---------------- k1: normalize rows, store bf16 ----------------
__global__ __launch_bounds__(256) void k_normalize(const float* __restrict__ feats,
                                                   unsigned short* __restrict__ nfb) {
  int tid = threadIdx.x;
  int lane = tid & 63;
  int row = blockIdx.x * 4 + (tid >> 6);
  float2 f = *(const float2*)(feats + (size_t)row * DD + lane * 2);
  float ss = f.x * f.x + f.y * f.y;
  #pragma unroll
  for (int m = 1; m < 64; m <<= 1) ss += __shfl_xor(ss, m);
  float rn = 1.0f / fmaxf(sqrtf(ss), 1e-8f);
  unsigned int lo = f2bf(f.x * rn), hi = f2bf(f.y * rn);
  *(unsigned int*)(nfb + (size_t)row * DD + lane * 2) = lo | (hi << 16);
}

// ---------------- diagnostic scan: 4 full passes over label ----------------
// NT=1: nontemporal loads; NT=0: plain loads. Identical otherwise.
// asm memory clobber between passes prevents CSE of the repeated loads.
template <int NT>
__global__ __launch_bounds__(256) void k_scan(const int* __restrict__ label,
                                              int* __restrict__ pos_idx) {
  int t = blockIdx.x * 256 + threadIdx.x;     // 524288 threads
  const u32x4* L = (const u32x4*)label;       // 16777216 vec4 elements
  for (int p = 0; p < 4; p++) {
    asm volatile("" ::: "memory");            // force re-execution of each pass
    #pragma unroll
    for (int k = 0; k < 4; k++) {
      u32x4 v[8];
      #pragma unroll
      for (int j = 0; j < 8; j++) {
        const u32x4* a = &L[t + (k * 8 + j) * 524288];
        v[j] = NT ? __builtin_nontemporal_load(a) : *a;
      }
      unsigned any = 0;
      #pragma unroll
      for (int j = 0; j < 8; j++) any |= v[j][0] | v[j][1] | v[j][2] | v[j][3];
      if (any) {
        #pragma unroll
        for (int j = 0; j < 8; j++) {
          if (v[j][0] | v[j][1] | v[j][2] | v[j][3]) {
            int gi = (t + (k * 8 + j) * 524288) * 4;
            int row = gi >> 13, col = gi & (NN - 1);
            if (v[j][0] == 1u) pos_idx[row] = col;
            if (v[j][1] == 1u) pos_idx[row] = col + 1;
            if (v[j][2] == 1u) pos_idx[row] = col + 2;
            if (v[j][3] == 1u) pos_idx[row] = col + 3;
          }
        }
      }
    }
  }
}

// ---------------- k2: barrier-free GEMM+LSE only (scan removed) ----------------
__global__ __launch_bounds__(256, 2) void k_gemm(const unsigned short* __restrict__ nfb,
                                                 float* __restrict__ lpart) {
  int g = blockIdx.x;              // 0..511
  int tid = threadIdx.x;
  int w = tid >> 6;                // wave 0..3 (independent)
  int lane = tid & 63;
  int lg = lane >> 4;              // lane group 0..3 (k-offset / C-row group)
  int ll = lane & 15;              // C column within 16-tile

  int r0 = (g >> 2) * 64;                    // 64-row band
  int cq = (g & 3) * 2048 + w * 512;         // this wave's private 512-col quarter

  // A fragments for all 64 rows: afr[ms][kc], row = r0+ms*16+ll, k = kc*32+lg*8
  bf16x8 afr[4][4];
  #pragma unroll
  for (int ms = 0; ms < 4; ms++) {
    const unsigned short* arow = nfb + (size_t)(r0 + ms * 16 + ll) * DD + lg * 8;
    #pragma unroll
    for (int kc = 0; kc < 4; kc++)
      afr[ms][kc] = *(const bf16x8*)(arow + kc * 32);
  }

  float lacc[4][4];
  #pragma unroll
  for (int ms = 0; ms < 4; ms++)
    #pragma unroll
    for (int r = 0; r < 4; r++) lacc[ms][r] = 0.f;

  for (int it = 0; it < 16; ++it) {
    int hcol = cq + it * 32;   // 32-col half-tile

    bf16x8 bfr[2][4];
    #pragma unroll
    for (int ns = 0; ns < 2; ns++) {
      const unsigned short* brow = nfb + (size_t)(hcol + ns * 16 + ll) * DD + lg * 8;
      #pragma unroll
      for (int kc = 0; kc < 4; kc++)
        bfr[ns][kc] = *(const bf16x8*)(brow + kc * 32);
    }

    f32x4 acc[4][2];
    #pragma unroll
    for (int ms = 0; ms < 4; ms++)
      #pragma unroll
      for (int ns = 0; ns < 2; ns++) acc[ms][ns] = (f32x4){0.f, 0.f, 0.f, 0.f};
    #pragma unroll
    for (int kc = 0; kc < 4; kc++)
      #pragma unroll
      for (int ns = 0; ns < 2; ns++)
        #pragma unroll
        for (int ms = 0; ms < 4; ms++)
          acc[ms][ns] = __builtin_amdgcn_mfma_f32_16x16x32_bf16(afr[ms][kc], bfr[ns][kc], acc[ms][ns], 0, 0, 0);

    bool mayDiag = (hcol < r0 + 64) && (hcol + 32 > r0);
    if (mayDiag) {
      #pragma unroll
      for (int ms = 0; ms < 4; ms++) {
        int growb = r0 + ms * 16 + lg * 4;
        #pragma unroll
        for (int ns = 0; ns < 2; ns++) {
          int gcol = hcol + ns * 16 + ll;
          #pragma unroll
          for (int r = 0; r < 4; r++) {
            float s = (growb + r == gcol) ? -3.0e38f : acc[ms][ns][r];
            lacc[ms][r] += __builtin_amdgcn_exp2f((s - 1.0f) * kScale);
          }
        }
      }
    } else {
      #pragma unroll
      for (int ms = 0; ms < 4; ms++)
        #pragma unroll
        for (int ns = 0; ns < 2; ns++)
          #pragma unroll
          for (int r = 0; r < 4; r++)
            lacc[ms][r] += __builtin_amdgcn_exp2f((acc[ms][ns][r] - 1.0f) * kScale);
    }
  }

  // reduce partial l across the 16 lanes (cols) of each group; per-wave slot.
  #pragma unroll
  for (int ms = 0; ms < 4; ms++)
    #pragma unroll
    for (int r = 0; r < 4; r++) {
      float v = lacc[ms][r];
      v += __shfl_xor(v, 1); v += __shfl_xor(v, 2);
      v += __shfl_xor(v, 4); v += __shfl_xor(v, 8);
      lacc[ms][r] = v;
    }
  if (ll == 0) {
    int slot = (g & 3) * 4 + w;    // 16 slots: col-strip x wave-quarter
    #pragma unroll
    for (int ms = 0; ms < 4; ms++)
      #pragma unroll
      for (int r = 0; r < 4; r++) {
        int grow = r0 + ms * 16 + lg * 4 + r;
        lpart[(size_t)slot * NN + grow] = lacc[ms][r];
      }
  }
}

// ---------------- k3: per-row lse + positive, block partial sums ----------------
__global__ __launch_bounds__(256) void k_finalize(const unsigned short* __restrict__ nfb,
                                                  const float* __restrict__ lpart,
                                                  const int* __restrict__ pos_idx,
                                                  float* __restrict__ bpart) {
  int i = blockIdx.x * 256 + threadIdx.x;
  float l = 0.f;
  #pragma unroll
  for (int s = 0; s < 16; s++) l += lpart[(size_t)s * NN + i];
  float lse = kM + __builtin_amdgcn_logf(l) * kLn2;
  int p = pos_idx[i] & (NN - 1);
  const u32x4* ri = (const u32x4*)(nfb + (size_t)i * DD);
  const u32x4* rp = (const u32x4*)(nfb + (size_t)p * DD);
  float dot = 0.f;
  #pragma unroll
  for (int c = 0; c < 16; c++) {
    u32x4 a = ri[c], bb = rp[c];
    #pragma unroll
    for (int e = 0; e < 4; e++) {
      float al = __uint_as_float(a[e] << 16), ah = __uint_as_float(a[e] & 0xFFFF0000u);
      float bl = __uint_as_float(bb[e] << 16), bh = __uint_as_float(bb[e] & 0xFFFF0000u);
      dot += al * bl + ah * bh;
    }
  }
  float val = lse - dot * kM;   // pos = dot / T
  #pragma unroll
  for (int m = 1; m < 64; m <<= 1) val += __shfl_xor(val, m);
  __shared__ float wsum[4];
  if ((threadIdx.x & 63) == 0) wsum[threadIdx.x >> 6] = val;
  __syncthreads();
  if (threadIdx.x == 0) bpart[blockIdx.x] = wsum[0] + wsum[1] + wsum[2] + wsum[3];
}

// ---------------- k4: final mean ----------------
__global__ void k_reduce(const float* __restrict__ bpart, float* __restrict__ out) {
  int t = threadIdx.x;
  float v = (t < 32) ? bpart[t] : 0.f;
  #pragma unroll
  for (int m = 1; m < 64; m <<= 1) v += __shfl_xor(v, m);
  if (t == 0) out[0] = v * (1.0f / (float)NN);
}

extern "C" void kernel_launch(void* const* d_in, const int* in_sizes, int n_in,
                              void* d_out, int out_size, void* d_ws, size_t ws_size,
                              hipStream_t stream) {
  (void)in_sizes; (void)n_in; (void)out_size; (void)ws_size;
  const float* feats = (const float*)d_in[0];
  const int* label = (const int*)d_in[1];
  float* out = (float*)d_out;

  char* ws = (char*)d_ws;
  unsigned short* nfb = (unsigned short*)ws;                    // 2 MB
  float* lpart = (float*)(ws + 2 * 1024 * 1024);                // 512 KB (16 slots)
  int* pos_idx = (int*)(ws + 2 * 1024 * 1024 + 524288);         // 32 KB
  float* bpart = (float*)(ws + 2 * 1024 * 1024 + 524288 + 32768);

  k_normalize<<<NN / 4, 256, 0, stream>>>(feats, nfb);
  k_scan<1><<<2048, 256, 0, stream>>>(label, pos_idx);   // NT loads, 4x256MB
  k_scan<0><<<2048, 256, 0, stream>>>(label, pos_idx);   // plain loads, 4x256MB
  k_gemm<<<512, 256, 0, stream>>>(nfb, lpart);
  k_finalize<<<NN / 256, 256, 0, stream>>>(nfb, lpart, pos_idx, bpart);
  k_reduce<<<1, 64, 0, stream>>>(bpart, out);
}

// Round 9
// 97.427 us; speedup vs baseline: 4.2199x; 4.2199x over previous
//
#include <hip/hip_runtime.h>

// ContrastiveLoss on MI355X.
// Round-8 diagnostic results baked in: NT==plain loads; label scan demand rate
// ~5.2 TB/s with ~50% LLC retention (label == LLC size); dedicated-scan pass
// = 52us at 16 waves/CU; fused round-7 k2 (8 waves/CU) = ~62us. Lever:
// occupancy of the fused kernel.
// Pipeline:
//   k1 normalize: feats fp32 [8192][128] -> nf bf16 (ws)
//   k2 fused LEAN (VGPR<=128 via __launch_bounds__(256,4), 1024 blocks = 4
//      resident blocks/CU = 16 waves/CU): per wave 32 rows x 512 cols of
//      S=nf@nf^T (both MFMA operands read directly from L2-resident nf; no
//      LDS, no barriers) + 64KB label-scan slice (4 u32x4 loads/iter issued
//      after B-frags -> MFMA waits leave them in flight; tested post-exp).
//   k3 finalize: per row lse = M + log(sum of 16 partials); pos = nf_i.nf_p/T;
//      block-reduce then atomicAdd(mean term) into d_out (memset to 0 first).
// ws usage: 2MB nf + 512KB lpart(16 slots) + 32KB pos_idx.

#define NN 8192
#define DD 128

typedef __bf16 bf16x8 __attribute__((ext_vector_type(8)));
typedef float f32x4 __attribute__((ext_vector_type(4)));
typedef unsigned int u32x4 __attribute__((ext_vector_type(4)));

constexpr float kM     = 1.0f / 0.07f;                    // fixed max bound (cos<=1)
constexpr float kScale = 1.4426950408889634f / 0.07f;     // log2(e)/T
constexpr float kLn2   = 0.6931471805599453f;

__device__ inline unsigned short f2bf(float f) {
  unsigned int u = __float_as_uint(f);
  unsigned int r = (u + 0x7FFFu + ((u >> 16) & 1u)) >> 16;  // RNE, no NaN inputs
  return (unsigned short)r;
}

// ---------------- k1: normalize rows, store bf16 ----------------
__global__ __launch_bounds__(256) void k_normalize(const float* __restrict__ feats,
                                                   unsigned short* __restrict__ nfb) {
  int tid = threadIdx.x;
  int lane = tid & 63;
  int row = blockIdx.x * 4 + (tid >> 6);
  float2 f = *(const float2*)(feats + (size_t)row * DD + lane * 2);
  float ss = f.x * f.x + f.y * f.y;
  #pragma unroll
  for (int m = 1; m < 64; m <<= 1) ss += __shfl_xor(ss, m);
  float rn = 1.0f / fmaxf(sqrtf(ss), 1e-8f);
  unsigned int lo = f2bf(f.x * rn), hi = f2bf(f.y * rn);
  *(unsigned int*)(nfb + (size_t)row * DD + lane * 2) = lo | (hi << 16);
}

// ---------------- k2: lean fused GEMM+LSE + label scan ----------------
__global__ __launch_bounds__(256, 4) void k_fused(const unsigned short* __restrict__ nfb,
                                                  const int* __restrict__ label,
                                                  float* __restrict__ lpart,
                                                  int* __restrict__ pos_idx) {
  int g = blockIdx.x;              // 0..1023
  int tid = threadIdx.x;
  int w = tid >> 6;                // wave 0..3 (independent)
  int lane = tid & 63;
  int lg = lane >> 4;              // lane group 0..3 (k-offset / C-row group)
  int ll = lane & 15;              // C column within 16-tile

  int r0 = (g >> 2) * 32;                    // 32-row band
  int cq = (g & 3) * 2048 + w * 512;         // this wave's private 512-col strip
  int wid = g * 4 + w;                       // 0..4095

  const u32x4* L = (const u32x4*)label;
  int sbase = wid * 4096 + lane;             // vec4 units; wave scans 64KB contiguous

  // A fragments for 32 rows: afr[ms][kc], row = r0+ms*16+ll, k = kc*32+lg*8
  bf16x8 afr[2][4];
  #pragma unroll
  for (int ms = 0; ms < 2; ms++) {
    const unsigned short* arow = nfb + (size_t)(r0 + ms * 16 + ll) * DD + lg * 8;
    #pragma unroll
    for (int kc = 0; kc < 4; kc++)
      afr[ms][kc] = *(const bf16x8*)(arow + kc * 32);
  }

  float lacc[2][4] = {{0.f, 0.f, 0.f, 0.f}, {0.f, 0.f, 0.f, 0.f}};

  for (int it = 0; it < 16; ++it) {
    int hcol = cq + it * 32;   // 32-col half-tile

    // B-fragment loads FIRST (oldest in vmcnt FIFO; L2-resident nf):
    // MFMA's wait for these leaves the (younger) scan loads in flight.
    bf16x8 bfr[2][4];
    #pragma unroll
    for (int ns = 0; ns < 2; ns++) {
      const unsigned short* brow = nfb + (size_t)(hcol + ns * 16 + ll) * DD + lg * 8;
      #pragma unroll
      for (int kc = 0; kc < 4; kc++)
        bfr[ns][kc] = *(const bf16x8*)(brow + kc * 32);
    }

    // label scan loads (4 KB/wave/iter)
    u32x4 sv[4];
    #pragma unroll
    for (int j = 0; j < 4; j++)
      sv[j] = *(&L[sbase + it * 256 + j * 64]);

    // MFMA
    f32x4 acc[2][2] = {{{0.f,0.f,0.f,0.f},{0.f,0.f,0.f,0.f}},
                       {{0.f,0.f,0.f,0.f},{0.f,0.f,0.f,0.f}}};
    #pragma unroll
    for (int kc = 0; kc < 4; kc++)
      #pragma unroll
      for (int ns = 0; ns < 2; ns++)
        #pragma unroll
        for (int ms = 0; ms < 2; ms++)
          acc[ms][ns] = __builtin_amdgcn_mfma_f32_16x16x32_bf16(afr[ms][kc], bfr[ns][kc], acc[ms][ns], 0, 0, 0);

    // fixed-max sum of exp; C layout: col=ll, row=lg*4+r
    bool mayDiag = (hcol < r0 + 32) && (hcol + 32 > r0);
    if (mayDiag) {
      #pragma unroll
      for (int ms = 0; ms < 2; ms++) {
        int growb = r0 + ms * 16 + lg * 4;
        #pragma unroll
        for (int ns = 0; ns < 2; ns++) {
          int gcol = hcol + ns * 16 + ll;
          #pragma unroll
          for (int r = 0; r < 4; r++) {
            float s = (growb + r == gcol) ? -3.0e38f : acc[ms][ns][r];
            lacc[ms][r] += __builtin_amdgcn_exp2f((s - 1.0f) * kScale);
          }
        }
      }
    } else {
      #pragma unroll
      for (int ms = 0; ms < 2; ms++)
        #pragma unroll
        for (int ns = 0; ns < 2; ns++)
          #pragma unroll
          for (int r = 0; r < 4; r++)
            lacc[ms][r] += __builtin_amdgcn_exp2f((acc[ms][ns][r] - 1.0f) * kScale);
    }

    // test the scan batch (issued ~600+ cycles ago; latency mostly covered)
    unsigned any = 0;
    #pragma unroll
    for (int j = 0; j < 4; j++) any |= sv[j][0] | sv[j][1] | sv[j][2] | sv[j][3];
    if (any) {
      #pragma unroll
      for (int j = 0; j < 4; j++) {
        if (sv[j][0] | sv[j][1] | sv[j][2] | sv[j][3]) {
          int gi = (sbase + it * 256 + j * 64) * 4;
          int row = gi >> 13, col = gi & (NN - 1);
          if (sv[j][0] == 1u) pos_idx[row] = col;
          if (sv[j][1] == 1u) pos_idx[row] = col + 1;
          if (sv[j][2] == 1u) pos_idx[row] = col + 2;
          if (sv[j][3] == 1u) pos_idx[row] = col + 3;
        }
      }
    }
  }

  // reduce partial l across the 16 lanes (cols) of each group; per-wave slot.
  #pragma unroll
  for (int ms = 0; ms < 2; ms++)
    #pragma unroll
    for (int r = 0; r < 4; r++) {
      float v = lacc[ms][r];
      v += __shfl_xor(v, 1); v += __shfl_xor(v, 2);
      v += __shfl_xor(v, 4); v += __shfl_xor(v, 8);
      lacc[ms][r] = v;
    }
  if (ll == 0) {
    int slot = (g & 3) * 4 + w;    // 16 slots: col-strip x wave
    #pragma unroll
    for (int ms = 0; ms < 2; ms++)
      #pragma unroll
      for (int r = 0; r < 4; r++) {
        int grow = r0 + ms * 16 + lg * 4 + r;
        lpart[(size_t)slot * NN + grow] = lacc[ms][r];
      }
  }
}

// ---------------- k3: per-row lse + positive, atomic mean ----------------
__global__ __launch_bounds__(256) void k_finalize(const unsigned short* __restrict__ nfb,
                                                  const float* __restrict__ lpart,
                                                  const int* __restrict__ pos_idx,
                                                  float* __restrict__ out) {
  int i = blockIdx.x * 256 + threadIdx.x;
  float l = 0.f;
  #pragma unroll
  for (int s = 0; s < 16; s++) l += lpart[(size_t)s * NN + i];
  float lse = kM + __builtin_amdgcn_logf(l) * kLn2;
  int p = pos_idx[i] & (NN - 1);
  const u32x4* ri = (const u32x4*)(nfb + (size_t)i * DD);
  const u32x4* rp = (const u32x4*)(nfb + (size_t)p * DD);
  float dot = 0.f;
  #pragma unroll
  for (int c = 0; c < 16; c++) {
    u32x4 a = ri[c], bb = rp[c];
    #pragma unroll
    for (int e = 0; e < 4; e++) {
      float al = __uint_as_float(a[e] << 16), ah = __uint_as_float(a[e] & 0xFFFF0000u);
      float bl = __uint_as_float(bb[e] << 16), bh = __uint_as_float(bb[e] & 0xFFFF0000u);
      dot += al * bl + ah * bh;
    }
  }
  float val = lse - dot * kM;   // pos = dot / T
  #pragma unroll
  for (int m = 1; m < 64; m <<= 1) val += __shfl_xor(val, m);
  __shared__ float wsum[4];
  if ((threadIdx.x & 63) == 0) wsum[threadIdx.x >> 6] = val;
  __syncthreads();
  if (threadIdx.x == 0)
    atomicAdd(out, (wsum[0] + wsum[1] + wsum[2] + wsum[3]) * (1.0f / (float)NN));
}

extern "C" void kernel_launch(void* const* d_in, const int* in_sizes, int n_in,
                              void* d_out, int out_size, void* d_ws, size_t ws_size,
                              hipStream_t stream) {
  (void)in_sizes; (void)n_in; (void)out_size; (void)ws_size;
  const float* feats = (const float*)d_in[0];
  const int* label = (const int*)d_in[1];
  float* out = (float*)d_out;

  char* ws = (char*)d_ws;
  unsigned short* nfb = (unsigned short*)ws;                    // 2 MB
  float* lpart = (float*)(ws + 2 * 1024 * 1024);                // 512 KB (16 slots)
  int* pos_idx = (int*)(ws + 2 * 1024 * 1024 + 524288);         // 32 KB

  hipMemsetAsync(out, 0, sizeof(float), stream);
  k_normalize<<<NN / 4, 256, 0, stream>>>(feats, nfb);
  k_fused<<<1024, 256, 0, stream>>>(nfb, label, lpart, pos_idx);
  k_finalize<<<NN / 256, 256, 0, stream>>>(nfb, lpart, pos_idx, out);
}

// Round 10
// 88.304 us; speedup vs baseline: 4.6559x; 1.1033x over previous
//
#include <hip/hip_runtime.h>

// ContrastiveLoss on MI355X.
// Measured facts driving this version:
//   - label scan has an AGGREGATE ceiling ~4.5-5 TB/s (r4: 128 CUs -> 4.1;
//     r8 dedicated: 256 CUs -> 4.9; per-CU rate falls with more CUs).
//   - co-resident block quads share (b & 255) [r3/r4: bit-0 == bit-3 result],
//     so type = f(b&255) specializes whole CUs with any ratio.
//   - r9 lesson: forcing VGPR<=128 on the fused tile spills -> regression.
// Pipeline:
//   k1 normalize: feats fp32 [8192][128] -> nf bf16 (ws)
//   k2 split-pool: (b&255)<160 -> scan pool (160 CUs, 640 blocks, 416KB
//      clamped slice each, 8-deep batches); else GEMM pool (96 CUs, 384
//      blocks stride-looping 512 units of the r4 LDS 64x64-tile body with
//      fixed-max sum-of-exp, diag skipped).
//   k3 finalize: lse = M + log(sum of 8 partials); pos = nf_i.nf_p/T;
//      block reduce -> atomicAdd(mean term) into d_out (memset to 0 first).
// ws: 2MB nf + 256KB lpart(8 slots) + 32KB pos_idx.

#define NN 8192
#define DD 128

typedef __bf16 bf16x8 __attribute__((ext_vector_type(8)));
typedef float f32x4 __attribute__((ext_vector_type(4)));
typedef unsigned int u32x4 __attribute__((ext_vector_type(4)));

constexpr float kM     = 1.0f / 0.07f;                    // fixed max bound (cos<=1)
constexpr float kScale = 1.4426950408889634f / 0.07f;     // log2(e)/T
constexpr float kLn2   = 0.6931471805599453f;

__device__ inline unsigned short f2bf(float f) {
  unsigned int u = __float_as_uint(f);
  unsigned int r = (u + 0x7FFFu + ((u >> 16) & 1u)) >> 16;  // RNE, no NaN inputs
  return (unsigned short)r;
}

// ---------------- k1: normalize rows, store bf16 ----------------
__global__ __launch_bounds__(256) void k_normalize(const float* __restrict__ feats,
                                                   unsigned short* __restrict__ nfb) {
  int tid = threadIdx.x;
  int lane = tid & 63;
  int row = blockIdx.x * 4 + (tid >> 6);
  float2 f = *(const float2*)(feats + (size_t)row * DD + lane * 2);
  float ss = f.x * f.x + f.y * f.y;
  #pragma unroll
  for (int m = 1; m < 64; m <<= 1) ss += __shfl_xor(ss, m);
  float rn = 1.0f / fmaxf(sqrtf(ss), 1e-8f);
  unsigned int lo = f2bf(f.x * rn), hi = f2bf(f.y * rn);
  *(unsigned int*)(nfb + (size_t)row * DD + lane * 2) = lo | (hi << 16);
}

// ---------------- k2: split-pool scan / GEMM+LSE ----------------
__global__ __launch_bounds__(256, 3) void k_fused(const unsigned short* __restrict__ nfb,
                                                  const int* __restrict__ label,
                                                  float* __restrict__ lpart,
                                                  int* __restrict__ pos_idx) {
  __shared__ __align__(16) unsigned short ldsB[64 * DD];  // 16KB, XOR-swizzled rows
  int b = blockIdx.x;
  int tid = threadIdx.x;
  int c = b & 255;                 // determines this block's CU -> pool purity
  if (c < 160) {
    // ---- scan pool: 640 blocks, contiguous clamped 26624-vec4 slices ----
    int s = (b >> 8) * 160 + c;                // 0..639
    const u32x4* L = (const u32x4*)label;
    int base = s * 26624 + tid;
    for (int bb = 0; bb < 13; ++bb) {
      u32x4 v[8];
      #pragma unroll
      for (int j = 0; j < 8; j++) {
        unsigned idx = (unsigned)(base + bb * 2048 + j * 256);
        idx = idx < 16777216u ? idx : 16777215u;   // clamp (idempotent reads)
        v[j] = L[idx];
      }
      unsigned any = 0;
      #pragma unroll
      for (int j = 0; j < 8; j++) any |= v[j][0] | v[j][1] | v[j][2] | v[j][3];
      if (any) {
        #pragma unroll
        for (int j = 0; j < 8; j++) {
          if (v[j][0] | v[j][1] | v[j][2] | v[j][3]) {
            unsigned idx = (unsigned)(base + bb * 2048 + j * 256);
            idx = idx < 16777216u ? idx : 16777215u;
            int gi = (int)idx * 4;
            int row = gi >> 13, col = gi & (NN - 1);
            if (v[j][0] == 1u) pos_idx[row] = col;
            if (v[j][1] == 1u) pos_idx[row] = col + 1;
            if (v[j][2] == 1u) pos_idx[row] = col + 2;
            if (v[j][3] == 1u) pos_idx[row] = col + 3;
          }
        }
      }
    }
  } else {
    // ---- GEMM pool: 384 blocks stride-loop 512 units (64 rows x 2048 cols) ----
    int p = (b >> 8) * 96 + (c - 160);         // 0..383
    int lane = tid & 63, w = tid >> 6;
    int wm = w >> 1, wn = w & 1;               // 2x2 wave grid
    int lg = lane >> 4;                        // lane group 0..3
    int ll = lane & 15;
    int slr = tid >> 4;                        // staging: local row base
    int sch = tid & 15;                        // staging: 16B chunk

    for (int u = p; u < 512; u += 384) {
      int r0 = (u >> 2) * 64;
      int c0 = (u & 3) * 2048;

      // A fragments: row = ll within 16-row subtile, k = kc*32 + lg*8 .. +7
      bf16x8 afr[2][4];
      #pragma unroll
      for (int ms = 0; ms < 2; ms++) {
        const unsigned short* arow = nfb + (size_t)(r0 + wm * 32 + ms * 16 + ll) * DD + lg * 8;
        #pragma unroll
        for (int kc = 0; kc < 4; kc++)
          afr[ms][kc] = *(const bf16x8*)(arow + kc * 32);
      }

      float lacc[2][4] = {{0.f, 0.f, 0.f, 0.f}, {0.f, 0.f, 0.f, 0.f}};

      for (int ct = 0; ct < 32; ct++) {
        int ctile = c0 + ct * 64;
        __syncthreads();
        // stage 64x128 bf16 B tile (rows = global cols), swizzled
        #pragma unroll
        for (int pp = 0; pp < 4; pp++) {
          int row = pp * 16 + slr;
          u32x4 v = *(const u32x4*)(nfb + (size_t)(ctile + row) * DD + sch * 8);
          *(u32x4*)((char*)ldsB + row * 256 + ((sch * 16) ^ ((row & 7) << 4))) = v;
        }
        __syncthreads();

        f32x4 acc[2][2] = {{{0.f,0.f,0.f,0.f},{0.f,0.f,0.f,0.f}},
                           {{0.f,0.f,0.f,0.f},{0.f,0.f,0.f,0.f}}};
        #pragma unroll
        for (int ns = 0; ns < 2; ns++) {
          int brow = wn * 32 + ns * 16 + ll;
          const char* bbase = (const char*)ldsB + brow * 256;
          int sw = (brow & 7) << 4;
          #pragma unroll
          for (int kc = 0; kc < 4; kc++) {
            bf16x8 bfr = *(const bf16x8*)(bbase + ((kc * 64 + lg * 16) ^ sw));
            acc[0][ns] = __builtin_amdgcn_mfma_f32_16x16x32_bf16(afr[0][kc], bfr, acc[0][ns], 0, 0, 0);
            acc[1][ns] = __builtin_amdgcn_mfma_f32_16x16x32_bf16(afr[1][kc], bfr, acc[1][ns], 0, 0, 0);
          }
        }

        // fixed-max sum of exp; C layout: col=ll, row=lg*4+r
        bool mayDiag = (ctile < r0 + 64) && (r0 < ctile + 64);
        if (mayDiag) {
          #pragma unroll
          for (int ms = 0; ms < 2; ms++) {
            int growb = r0 + wm * 32 + ms * 16 + lg * 4;
            #pragma unroll
            for (int ns = 0; ns < 2; ns++) {
              int gcol = ctile + wn * 32 + ns * 16 + ll;
              #pragma unroll
              for (int r = 0; r < 4; r++) {
                float sv = (growb + r == gcol) ? -3.0e38f : acc[ms][ns][r];
                lacc[ms][r] += __builtin_amdgcn_exp2f((sv - 1.0f) * kScale);
              }
            }
          }
        } else {
          #pragma unroll
          for (int ms = 0; ms < 2; ms++)
            #pragma unroll
            for (int ns = 0; ns < 2; ns++)
              #pragma unroll
              for (int r = 0; r < 4; r++)
                lacc[ms][r] += __builtin_amdgcn_exp2f((acc[ms][ns][r] - 1.0f) * kScale);
        }
      }

      // reduce partial l across the 16 lanes of each group; wn-distinct slots.
      #pragma unroll
      for (int ms = 0; ms < 2; ms++)
        #pragma unroll
        for (int r = 0; r < 4; r++) {
          float v = lacc[ms][r];
          v += __shfl_xor(v, 1); v += __shfl_xor(v, 2);
          v += __shfl_xor(v, 4); v += __shfl_xor(v, 8);
          lacc[ms][r] = v;
        }
      if (ll == 0) {
        int slot = (u & 3) * 2 + wn;
        #pragma unroll
        for (int ms = 0; ms < 2; ms++)
          #pragma unroll
          for (int r = 0; r < 4; r++) {
            int grow = r0 + wm * 32 + ms * 16 + lg * 4 + r;
            lpart[(size_t)slot * NN + grow] = lacc[ms][r];
          }
      }
    }
  }
}

// ---------------- k3: per-row lse + positive, atomic mean ----------------
__global__ __launch_bounds__(256) void k_finalize(const unsigned short* __restrict__ nfb,
                                                  const float* __restrict__ lpart,
                                                  const int* __restrict__ pos_idx,
                                                  float* __restrict__ out) {
  int i = blockIdx.x * 256 + threadIdx.x;
  float l = 0.f;
  #pragma unroll
  for (int s = 0; s < 8; s++) l += lpart[(size_t)s * NN + i];
  float lse = kM + __builtin_amdgcn_logf(l) * kLn2;
  int p = pos_idx[i] & (NN - 1);
  const u32x4* ri = (const u32x4*)(nfb + (size_t)i * DD);
  const u32x4* rp = (const u32x4*)(nfb + (size_t)p * DD);
  float dot = 0.f;
  #pragma unroll
  for (int c = 0; c < 16; c++) {
    u32x4 a = ri[c], bb = rp[c];
    #pragma unroll
    for (int e = 0; e < 4; e++) {
      float al = __uint_as_float(a[e] << 16), ah = __uint_as_float(a[e] & 0xFFFF0000u);
      float bl = __uint_as_float(bb[e] << 16), bh = __uint_as_float(bb[e] & 0xFFFF0000u);
      dot += al * bl + ah * bh;
    }
  }
  float val = lse - dot * kM;   // pos = dot / T
  #pragma unroll
  for (int m = 1; m < 64; m <<= 1) val += __shfl_xor(val, m);
  __shared__ float wsum[4];
  if ((threadIdx.x & 63) == 0) wsum[threadIdx.x >> 6] = val;
  __syncthreads();
  if (threadIdx.x == 0)
    atomicAdd(out, (wsum[0] + wsum[1] + wsum[2] + wsum[3]) * (1.0f / (float)NN));
}

extern "C" void kernel_launch(void* const* d_in, const int* in_sizes, int n_in,
                              void* d_out, int out_size, void* d_ws, size_t ws_size,
                              hipStream_t stream) {
  (void)in_sizes; (void)n_in; (void)out_size; (void)ws_size;
  const float* feats = (const float*)d_in[0];
  const int* label = (const int*)d_in[1];
  float* out = (float*)d_out;

  char* ws = (char*)d_ws;
  unsigned short* nfb = (unsigned short*)ws;                    // 2 MB
  float* lpart = (float*)(ws + 2 * 1024 * 1024);                // 256 KB (8 slots)
  int* pos_idx = (int*)(ws + 2 * 1024 * 1024 + 262144);         // 32 KB

  hipMemsetAsync(out, 0, sizeof(float), stream);
  k_normalize<<<NN / 4, 256, 0, stream>>>(feats, nfb);
  k_fused<<<1024, 256, 0, stream>>>(nfb, label, lpart, pos_idx);
  k_finalize<<<NN / 256, 256, 0, stream>>>(nfb, lpart, pos_idx, out);
}